// Round 16
// baseline (150.567 us; speedup 1.0000x reference)
//
#include <hip/hip_runtime.h>
#include <hip/hip_bf16.h>

#define IMG 224
#define NPS 14
#define NP  196
#define BATCH 64
#define PD  3840
#define PROJ 768
#define M_TOT (BATCH*NP)        // 12544
#define TOK_SIZE (M_TOT*PROJ)   // 9633792
#define KT  120                 // PD/32
#define MT  98                  // M_TOT/128
#define NT  6                   // PROJ/128
#define TILE_BYTES 8192         // 128x32 bf16 tile
#define IMG_BYTES 38535168      // 64*224*224*3*4

typedef __attribute__((ext_vector_type(8))) __bf16 bf16x8;
typedef __attribute__((ext_vector_type(4))) float f32x4;

__device__ __forceinline__ unsigned short f2bf(float f) {
    unsigned int u = __builtin_bit_cast(unsigned int, f);
    u += 0x7FFFu + ((u >> 16) & 1u);
    return (unsigned short)(u >> 16);
}

// prep-internal pbuf swizzle: XOR byte-addr bits[6:4] with bits[11:9].
__device__ __forceinline__ int swz(int a) { return a ^ (((a >> 9) & 7) << 4); }

#define GLD16(gsrc, ldst) __builtin_amdgcn_global_load_lds( \
    (const __attribute__((address_space(1))) unsigned int*)(gsrc), \
    (__attribute__((address_space(3))) unsigned int*)(ldst), 16, 0, 0)

// ============== FAST PATH ==============

// prepw: fused prep (blocks 0..1023, XCD-colocated patch ranges) +
// W-transpose (blocks 1024..1743).
// prep path: tiled-BK32 Aws, paired full-line stores, T14 async split.
// T1 swizzle: each XCD gets 16 heavy(14-patch) + 112 light(12-patch) blocks
// = 1568 patches in two contiguous runs -> halo rows shared by adjacent
// patch strips stay in the same XCD's L2.
__global__ __launch_bounds__(512, 4) void prepw_kernel(
    const float* __restrict__ images, const float* __restrict__ gamma,
    const float* __restrict__ beta, const float* __restrict__ W,
    float* __restrict__ patches_out, char* __restrict__ Aws,
    char* __restrict__ Bws) {
  __shared__ __align__(16) char smem[32960];
  const int t = threadIdx.x;

  if (blockIdx.x >= 1024) {
    // ---------- W-transpose path ----------
    float (*wtile)[32][33] = (float (*)[32][33])smem;
    const int wb = blockIdx.x - 1024;
    const int half = t >> 8;          // 0 or 1
    const int tid = t & 255;
    const int nl = tid & 31;
    #pragma unroll
    for (int rep = 0; rep < 2; ++rep) {
      int idx = wb*4 + rep*2 + half;  // 0..2879
      int bx = idx % 24;              // n-tile
      int by = idx / 24;              // k-tile
      #pragma unroll
      for (int r = 0; r < 4; ++r) {
        int kl = (tid >> 5) + r*8;
        wtile[half][nl][kl] = W[(by*32 + kl)*PROJ + bx*32 + nl];
      }
      __syncthreads();
      if (tid < 128) {
        const int n_local = tid >> 2;
        const int kchunk  = tid & 3;
        unsigned int u[4];
        #pragma unroll
        for (int j = 0; j < 4; ++j) {
          unsigned short lo = f2bf(wtile[half][n_local][kchunk*8 + j*2]);
          unsigned short hi = f2bf(wtile[half][n_local][kchunk*8 + j*2 + 1]);
          u[j] = (unsigned)lo | ((unsigned)hi << 16);
        }
        const int n = bx*32 + n_local;
        const int ntile = n >> 7, nrow = n & 127;
        const int byteoff = (nrow*64 + (kchunk*8)*2) ^ ((nrow & 7) << 4);
        *(uint4*)(Bws + ((size_t)(ntile*KT + by))*TILE_BYTES + byteoff) =
            make_uint4(u[0], u[1], u[2], u[3]);
      }
      __syncthreads();
    }
    return;
  }

  // ---------- prep path ----------
  char* const pb = smem;
  float (*red_s)[8] = (float (*)[8])(smem + 32768);
  float (*red_q)[8] = (float (*)[8])(smem + 32832);

  int relv[2];
  int la[2][4];
  int iof8[2];
  unsigned jpk[2];
  #pragma unroll
  for (int u = 0; u < 2; ++u) {
    int uu = t + u*512;
    if (uu < 960) {
      int run = uu / 12, slot = uu - run*12;
      int g = run >> 4, p = run & 15;
      int dh = (g==0) ? 0 : ((g & 1) ? 8 : -8);
      int dw = (g==0) ? 0 : ((g <= 2) ? 8 : -8);
      int ioff = p + dh;
      relv[u] = ((ioff*224 + dw)*3 + slot*4)*4 + 32768;
      iof8[u] = ioff + 8;
      int i48 = slot*4;
      int q0 = i48/3, c0 = i48 - q0*3;
      int dbase = (p*16 + q0)*15 + g*3 + c0;
      int dd1 = (c0==2) ? 13 : 1;
      int dd2 = (c0==0) ? 2 : 14;
      la[u][0] = swz(dbase*4);
      la[u][1] = swz((dbase+dd1)*4);
      la[u][2] = swz((dbase+dd2)*4);
      la[u][3] = swz((dbase+15)*4);
      unsigned jp = 0;
      #pragma unroll
      for (int k = 0; k < 4; ++k) {
        int qk = q0 + ((c0 + k) >= 3 ? 1 : 0);
        jp |= (unsigned)(dw + qk + 8) << (8*k);
      }
      jpk[u] = jp;
    } else {
      relv[u] = 32768; iof8[u] = 0; jpk[u] = 0;
      la[u][0] = swz(4000*4); la[u][1] = swz(4001*4);
      la[u][2] = swz(4002*4); la[u][3] = swz(4003*4);
    }
  }

  const int d0 = (t < 480) ? t*8 : 0;
  const int rba = swz(d0*4);
  const int rbb = swz(d0*4 + 16);
  const int tileoff_t = (t >> 2)*TILE_BYTES;
  const int chunk16   = (t & 3)*16;
  float4 g8a = *(const float4*)(gamma + d0);
  float4 g8b = *(const float4*)(gamma + d0 + 4);
  float4 b8a = *(const float4*)(beta + d0);
  float4 b8b = *(const float4*)(beta + d0 + 4);

  auto do_loads = [&](int np, int toggle) -> float2 {
    int b  = np / NP;
    int pp = np - b*NP;
    int ph = pp / NPS;
    int pw = pp - ph*NPS;
    int pixoff = (b*50176 + (ph*224 + pw)*16)*12;
    const char* sbase = (const char*)images + (pixoff - 32768);
    float s = 0.f, q = 0.f;
    char* lb = pb + toggle;
    if (ph != 0 && ph != 13 && pw != 0 && pw != 13) {
      #pragma unroll
      for (int u = 0; u < 2; ++u) {
        if (u == 0 || t < 448) {
          float4 v4 = *(const float4*)(sbase + relv[u]);
          s += (v4.x + v4.y) + (v4.z + v4.w);
          q += (v4.x*v4.x + v4.y*v4.y) + (v4.z*v4.z + v4.w*v4.w);
          *(float*)(lb + la[u][0]) = v4.x;
          *(float*)(lb + la[u][1]) = v4.y;
          *(float*)(lb + la[u][2]) = v4.z;
          *(float*)(lb + la[u][3]) = v4.w;
        }
      }
    } else {
      int ph16 = ph*16 - 8, pw16 = pw*16 - 8;
      int lo = 32768 - pixoff;
      int hi = IMG_BYTES - pixoff + 32768 - 16;
      #pragma unroll
      for (int u = 0; u < 2; ++u) {
        if (u == 0 || t < 448) {
          int ii = ph16 + iof8[u];
          bool rowok = (unsigned)ii < 224u;
          int vo = rowok ? relv[u] : 32768;
          vo = vo < lo ? lo : vo;
          vo = vo > hi ? hi : vo;
          float4 v4 = *(const float4*)(sbase + vo);
          float vv0 = v4.x, vv1 = v4.y, vv2 = v4.z, vv3 = v4.w;
          #pragma unroll
          for (int k = 0; k < 4; ++k) {
            int jj = pw16 + (int)((jpk[u] >> (8*k)) & 255u);
            float x = (k==0?vv0:(k==1?vv1:(k==2?vv2:vv3)));
            x = (rowok && (unsigned)jj < 224u) ? x : 0.f;
            s += x; q += x*x;
            *(float*)(lb + la[u][k]) = x;
          }
        }
      }
    }
    return make_float2(s, q);
  };

  // T1 XCD-colocate (bijective, load-balanced): 1024 = 8 XCDs x 128 pos.
  // Each XCD gets 16 heavy(14) + 112 light(12) blocks = 1568 patches.
  const int bi0 = blockIdx.x;
  const int xcd = bi0 & 7, pos = bi0 >> 3;
  const int bi = (pos < 16) ? (xcd*16 + pos) : (128 + xcd*112 + (pos - 16));
  const int start = 2*(bi*6 + (bi < 128 ? bi : 128));
  const int cnt = (bi < 128) ? 14 : 12;

  float2 curps = do_loads(start, 0);
  asm volatile("s_waitcnt lgkmcnt(0)" ::: "memory");
  __builtin_amdgcn_s_barrier();
  __builtin_amdgcn_sched_barrier(0);

  int cur = 0;
  unsigned ue0=0, ue1=0, ue2=0, ue3=0;

  for (int j = 0; j < cnt; ++j) {
    const int p_ = start + j;
    float4 va = *(const float4*)(pb + (cur << 14) + rba);
    float4 vb = *(const float4*)(pb + (cur << 14) + rbb);

    float4 w0 = make_float4(0.f,0.f,0.f,0.f);
    float4 w1 = make_float4(0.f,0.f,0.f,0.f);
    int pw16_n = 0, flags = 0;
    if (j + 1 < cnt) {
      int np = p_ + 1;
      int b  = np / NP;
      int pp = np - b*NP;
      int ph = pp / NPS;
      int pw = pp - ph*NPS;
      int pixoff = (b*50176 + (ph*224 + pw)*16)*12;
      const char* sbase = (const char*)images + (pixoff - 32768);
      if (ph != 0 && ph != 13 && pw != 0 && pw != 13) {
        flags = 3;
        w0 = *(const float4*)(sbase + relv[0]);
        if (t < 448) w1 = *(const float4*)(sbase + relv[1]);
      } else {
        int ph16 = ph*16 - 8;
        pw16_n = pw*16 - 8;
        int lo = 32768 - pixoff;
        int hi = IMG_BYTES - pixoff + 32768 - 16;
        flags = 4;
        {
          int ii = ph16 + iof8[0];
          bool rowok = (unsigned)ii < 224u;
          int vo = rowok ? relv[0] : 32768;
          vo = vo < lo ? lo : vo;
          vo = vo > hi ? hi : vo;
          w0 = *(const float4*)(sbase + vo);
          if (rowok) flags |= 1;
        }
        if (t < 448) {
          int ii = ph16 + iof8[1];
          bool rowok = (unsigned)ii < 224u;
          int vo = rowok ? relv[1] : 32768;
          vo = vo < lo ? lo : vo;
          vo = vo > hi ? hi : vo;
          w1 = *(const float4*)(sbase + vo);
          if (rowok) flags |= 2;
        }
      }
    }

    float s = curps.x, q = curps.y;
    #pragma unroll
    for (int o = 32; o > 0; o >>= 1) { s += __shfl_xor(s, o); q += __shfl_xor(q, o); }
    if ((t & 63) == 0) { red_s[cur][t >> 6] = s; red_q[cur][t >> 6] = q; }
    asm volatile("s_waitcnt lgkmcnt(0)" ::: "memory");
    __builtin_amdgcn_s_barrier();
    __builtin_amdgcn_sched_barrier(0);

    {
      const float* rs = red_s[cur]; const float* rq = red_q[cur];
      float4 sa = *(const float4*)rs;  float4 sb = *(const float4*)(rs + 4);
      float4 qa = *(const float4*)rq;  float4 qb = *(const float4*)(rq + 4);
      float S = ((sa.x+sa.y)+(sa.z+sa.w)) + ((sb.x+sb.y)+(sb.z+sb.w));
      float Q = ((qa.x+qa.y)+(qa.z+qa.w)) + ((qb.x+qb.y)+(qb.z+qb.w));
      float mean = S * (1.f/PD);
      float rstd = rsqrtf(Q*(1.f/PD) - mean*mean + 1e-6f);
      if (t < 480) {
        float* po = patches_out + (size_t)p_*PD + d0;
        f32x4 vva = __builtin_bit_cast(f32x4, va);
        f32x4 vvb = __builtin_bit_cast(f32x4, vb);
        __builtin_nontemporal_store(vva, (f32x4*)po);
        __builtin_nontemporal_store(vvb, (f32x4*)(po + 4));
        float f0 = fmaf(va.x - mean, rstd*g8a.x, b8a.x);
        float f1 = fmaf(va.y - mean, rstd*g8a.y, b8a.y);
        float f2 = fmaf(va.z - mean, rstd*g8a.z, b8a.z);
        float f3 = fmaf(va.w - mean, rstd*g8a.w, b8a.w);
        float f4 = fmaf(vb.x - mean, rstd*g8b.x, b8b.x);
        float f5 = fmaf(vb.y - mean, rstd*g8b.y, b8b.y);
        float f6 = fmaf(vb.z - mean, rstd*g8b.z, b8b.z);
        float f7 = fmaf(vb.w - mean, rstd*g8b.w, b8b.w);
        unsigned u0, u1, u2, u3;
        asm("v_cvt_pk_bf16_f32 %0, %1, %2" : "=v"(u0) : "v"(f0), "v"(f1));
        asm("v_cvt_pk_bf16_f32 %0, %1, %2" : "=v"(u1) : "v"(f2), "v"(f3));
        asm("v_cvt_pk_bf16_f32 %0, %1, %2" : "=v"(u2) : "v"(f4), "v"(f5));
        asm("v_cvt_pk_bf16_f32 %0, %1, %2" : "=v"(u3) : "v"(f6), "v"(f7));
        if ((j & 1) == 0) {
          ue0 = u0; ue1 = u1; ue2 = u2; ue3 = u3;
        } else {
          const int mrow1 = p_ & 127;
          const int mrow0 = mrow1 - 1;
          size_t tbase = (size_t)(p_ >> 7)*(KT*TILE_BYTES) + tileoff_t;
          int off0 = (mrow0*64 + chunk16) ^ ((mrow0 & 7) << 4);
          int off1 = (mrow1*64 + chunk16) ^ ((mrow1 & 7) << 4);
          *(uint4*)(Aws + tbase + off0) = make_uint4(ue0, ue1, ue2, ue3);
          *(uint4*)(Aws + tbase + off1) = make_uint4(u0, u1, u2, u3);
        }
      }
    }

    float2 nps = make_float2(0.f, 0.f);
    if (j + 1 < cnt) {
      char* lb = pb + ((cur ^ 1) << 14);
      float ss = 0.f, qq = 0.f;
      if (!(flags & 4)) {
        ss += (w0.x + w0.y) + (w0.z + w0.w);
        qq += (w0.x*w0.x + w0.y*w0.y) + (w0.z*w0.z + w0.w*w0.w);
        *(float*)(lb + la[0][0]) = w0.x;
        *(float*)(lb + la[0][1]) = w0.y;
        *(float*)(lb + la[0][2]) = w0.z;
        *(float*)(lb + la[0][3]) = w0.w;
        if (t < 448) {
          ss += (w1.x + w1.y) + (w1.z + w1.w);
          qq += (w1.x*w1.x + w1.y*w1.y) + (w1.z*w1.z + w1.w*w1.w);
          *(float*)(lb + la[1][0]) = w1.x;
          *(float*)(lb + la[1][1]) = w1.y;
          *(float*)(lb + la[1][2]) = w1.z;
          *(float*)(lb + la[1][3]) = w1.w;
        }
      } else {
        #pragma unroll
        for (int u = 0; u < 2; ++u) {
          if (u == 0 || t < 448) {
            float4 v4 = u ? w1 : w0;
            bool rowok = (flags >> u) & 1;
            float vv0 = v4.x, vv1 = v4.y, vv2 = v4.z, vv3 = v4.w;
            #pragma unroll
            for (int k = 0; k < 4; ++k) {
              int jj = pw16_n + (int)((jpk[u] >> (8*k)) & 255u);
              float x = (k==0?vv0:(k==1?vv1:(k==2?vv2:vv3)));
              x = (rowok && (unsigned)jj < 224u) ? x : 0.f;
              ss += x; qq += x*x;
              *(float*)(lb + la[u][k]) = x;
            }
          }
        }
      }
      nps = make_float2(ss, qq);
    }

    asm volatile("s_waitcnt lgkmcnt(0)" ::: "memory");
    __builtin_amdgcn_s_barrier();
    __builtin_amdgcn_sched_barrier(0);
    curps = nps; cur ^= 1;
  }
}

// gemm5b: gemm5 with ring-4 A staging (frozen from round 15).
__global__ __launch_bounds__(256) void gemm5b_kernel(
    const char* __restrict__ Aws, const char* __restrict__ Bws,
    const float* __restrict__ bias, float* __restrict__ tokens) {
  __shared__ __align__(16) char lds4[4][TILE_BYTES];   // 32 KB, A only
  const int bid = blockIdx.x;
  const int xcd = bid & 7, pos = bid >> 3;
  const int virt = (xcd < 4) ? xcd*74 + pos : 296 + (xcd - 4)*73 + pos;
  const int bm = virt / 6;
  const int bn = virt - bm*6;

  const int t = threadIdx.x;
  const int l = t & 63;
  const int w = t >> 6;
  const int wr = w >> 1, wc = w & 1;
  const int lrow = l & 15;
  const int lk   = l >> 4;

  const char* Ag = Aws + (size_t)bm*KT*TILE_BYTES;
  const char* Bg = Bws + (size_t)bn*KT*TILE_BYTES;
  const int ga0 = w*1024 + l*16;
  const int ga1 = 4096 + w*1024 + l*16;
  const int da0 = w*1024;
  const int da1 = 4096 + w*1024;

  int aoff[4], bloc[4];
  #pragma unroll
  for (int fr = 0; fr < 4; ++fr) {
    int row = wr*64 + fr*16 + lrow;
    aoff[fr] = (row*64 + lk*16) ^ ((row & 7) << 4);
  }
  #pragma unroll
  for (int fc = 0; fc < 4; ++fc) {
    int row = wc*64 + fc*16 + lrow;
    bloc[fc] = (row*64 + lk*16) ^ ((row & 7) << 4);
  }

  f32x4 acc[4][4];
  #pragma unroll
  for (int i = 0; i < 4; ++i)
    #pragma unroll
    for (int j = 0; j < 4; ++j) acc[i][j] = f32x4{0.f, 0.f, 0.f, 0.f};

  auto STAGE_A = [&](int kt, char* base) {
    const size_t off = (size_t)kt * TILE_BYTES;
    GLD16(Ag + off + ga0, base + da0);
    GLD16(Ag + off + ga1, base + da1);
  };

  char* curb = &lds4[0][0];
  char* n1   = &lds4[1][0];
  char* n2   = &lds4[2][0];
  char* spare= &lds4[3][0];

  bf16x8 bf[4];
  #pragma unroll
  for (int fc = 0; fc < 4; ++fc) bf[fc] = *(const bf16x8*)(Bg + bloc[fc]);
  __builtin_amdgcn_sched_barrier(0);
  STAGE_A(0, curb);
  STAGE_A(1, n1);
  STAGE_A(2, n2);

  for (int kt = 0; kt < KT; ++kt) {
    if (kt == 0)           asm volatile("s_waitcnt vmcnt(4)" ::: "memory");
    else if (kt < KT - 2)  asm volatile("s_waitcnt vmcnt(2)" ::: "memory");
    else                   asm volatile("s_waitcnt vmcnt(0)" ::: "memory");
    __builtin_amdgcn_s_barrier();
    __builtin_amdgcn_sched_barrier(0);
    bf16x8 af[4];
    #pragma unroll
    for (int fr = 0; fr < 4; ++fr) af[fr] = *(const bf16x8*)(curb + aoff[fr]);
    #pragma unroll
    for (int fr = 0; fr < 4; ++fr)
      #pragma unroll
      for (int fc = 0; fc < 4; ++fc)
        acc[fr][fc] = __builtin_amdgcn_mfma_f32_16x16x32_bf16(
            af[fr], bf[fc], acc[fr][fc], 0, 0, 0);
    if (kt + 1 < KT) {
      const char* bsrc = Bg + (size_t)(kt + 1)*TILE_BYTES;
      #pragma unroll
      for (int fc = 0; fc < 4; ++fc) bf[fc] = *(const bf16x8*)(bsrc + bloc[fc]);
    }
    __builtin_amdgcn_sched_barrier(0);
    if (kt + 3 < KT) STAGE_A(kt + 3, spare);
    char* tmp = curb; curb = n1; n1 = n2; n2 = spare; spare = tmp;
  }

  const int m0 = bm * 128, n0 = bn * 128;
  #pragma unroll
  for (int fr = 0; fr < 4; ++fr) {
    int mrow = m0 + wr*64 + fr*16 + lk*4;
    #pragma unroll
    for (int fc = 0; fc < 4; ++fc) {
      int col = n0 + wc*64 + fc*16 + lrow;
      float bb = bias[col];
      #pragma unroll
      for (int i = 0; i < 4; ++i)
        __builtin_nontemporal_store(acc[fr][fc][i] + bb,
                                    &tokens[(size_t)(mrow + i)*PROJ + col]);
    }
  }
}

// ============== FALLBACK PATH (round-1, known-passing) ==============

__global__ __launch_bounds__(256) void prep_kernel(
    const float* __restrict__ images, float* __restrict__ patches_out,
    float2* __restrict__ mr) {
  const int pid = blockIdx.x;
  const int b  = pid / NP;
  const int pp = pid - b*NP;
  const int ph = pp / NPS;
  const int pw = pp - ph*NPS;
  const int t = threadIdx.x;
  float s = 0.f, s2 = 0.f;
  #pragma unroll
  for (int r = 0; r < 15; ++r) {
    int d   = t + r*256;
    int ch5 = d % 15;
    int rem = d / 15;
    int q = rem & 15;
    int p = rem >> 4;
    int g = ch5 / 3;
    int c = ch5 - g*3;
    int dh = (g==0) ? 0 : ((g & 1) ? 8 : -8);
    int dw = (g==0) ? 0 : ((g <= 2) ? 8 : -8);
    int ii = ph*16 + p + dh;
    int jj = pw*16 + q + dw;
    float v = 0.f;
    if ((unsigned)ii < IMG && (unsigned)jj < IMG)
      v = images[((b*IMG + ii)*IMG + jj)*3 + c];
    s += v; s2 += v*v;
    patches_out[(size_t)pid*PD + d] = v;
  }
  #pragma unroll
  for (int o = 32; o > 0; o >>= 1) { s += __shfl_xor(s, o); s2 += __shfl_xor(s2, o); }
  __shared__ float red[8];
  int w = t >> 6;
  if ((t & 63) == 0) { red[w*2] = s; red[w*2+1] = s2; }
  __syncthreads();
  if (t == 0) {
    float S  = red[0]+red[2]+red[4]+red[6];
    float S2 = red[1]+red[3]+red[5]+red[7];
    float mean = S * (1.f/PD);
    float var  = S2 * (1.f/PD) - mean*mean;
    mr[pid] = make_float2(mean, rsqrtf(var + 1e-6f));
  }
}

__global__ __launch_bounds__(256) void wtransr_kernel(
    const float* __restrict__ W, unsigned short* __restrict__ Wt) {
  __shared__ float tile[32][33];
  const int bx = blockIdx.x;
  const int by = blockIdx.y;
  const int tx = threadIdx.x & 31;
  const int ty = threadIdx.x >> 5;
  #pragma unroll
  for (int r = 0; r < 4; ++r)
    tile[ty + r*8][tx] = W[(by*32 + ty + r*8)*PROJ + bx*32 + tx];
  __syncthreads();
  #pragma unroll
  for (int r = 0; r < 4; ++r)
    Wt[(size_t)(bx*32 + ty + r*8)*PD + by*32 + tx] = f2bf(tile[tx][ty + r*8]);
}

__global__ __launch_bounds__(256) void gemm_kernel(
    const float* __restrict__ patches, const float2* __restrict__ mr,
    const float* __restrict__ gamma, const float* __restrict__ beta,
    const unsigned short* __restrict__ Wt, const float* __restrict__ bias,
    float* __restrict__ tokens) {
  __shared__ unsigned short Alds[128][40];
  const int bn = blockIdx.x;
  const int bm = blockIdx.y;
  const int t = threadIdx.x;
  const int l = t & 63;
  const int w = t >> 6;
  const int wr = w >> 1, wc = w & 1;
  const int m0 = bm * 128, n0 = bn * 128;
  const int lrow = l & 15, lk = l >> 4;
  const unsigned short* bp[4];
  #pragma unroll
  for (int fc = 0; fc < 4; ++fc)
    bp[fc] = Wt + (size_t)(n0 + wc*64 + fc*16 + lrow) * PD + lk*8;
  const int srow = t >> 3;
  const int skq  = (t & 7) * 4;
  f32x4 acc[4][4];
  #pragma unroll
  for (int i = 0; i < 4; ++i)
    #pragma unroll
    for (int j = 0; j < 4; ++j) acc[i][j] = f32x4{0.f, 0.f, 0.f, 0.f};
  bf16x8 bfrag[4], bnext[4];
  #pragma unroll
  for (int fc = 0; fc < 4; ++fc) bfrag[fc] = *reinterpret_cast<const bf16x8*>(bp[fc]);
  for (int kt = 0; kt < KT; ++kt) {
    const int k0 = kt * 32;
    #pragma unroll
    for (int pass = 0; pass < 4; ++pass) {
      int row = pass*32 + srow;
      int m = m0 + row;
      float2 mrv = mr[m];
      const float4 v  = *reinterpret_cast<const float4*>(patches + (size_t)m*PD + k0 + skq);
      const float4 gv = *reinterpret_cast<const float4*>(gamma + k0 + skq);
      const float4 bv = *reinterpret_cast<const float4*>(beta  + k0 + skq);
      ushort4 o;
      o.x = f2bf((v.x - mrv.x)*mrv.y*gv.x + bv.x);
      o.y = f2bf((v.y - mrv.x)*mrv.y*gv.y + bv.y);
      o.z = f2bf((v.z - mrv.x)*mrv.y*gv.z + bv.z);
      o.w = f2bf((v.w - mrv.x)*mrv.y*gv.w + bv.w);
      *reinterpret_cast<ushort4*>(&Alds[row][skq]) = o;
    }
    if (kt < KT-1) {
      #pragma unroll
      for (int fc = 0; fc < 4; ++fc)
        bnext[fc] = *reinterpret_cast<const bf16x8*>(bp[fc] + k0 + 32);
    }
    __syncthreads();
    bf16x8 afrag[4];
    #pragma unroll
    for (int fr = 0; fr < 4; ++fr)
      afrag[fr] = *reinterpret_cast<const bf16x8*>(&Alds[wr*64 + fr*16 + lrow][lk*8]);
    #pragma unroll
    for (int fr = 0; fr < 4; ++fr)
      #pragma unroll
      for (int fc = 0; fc < 4; ++fc)
        acc[fr][fc] = __builtin_amdgcn_mfma_f32_16x16x32_bf16(
            afrag[fr], bfrag[fc], acc[fr][fc], 0, 0, 0);
    __syncthreads();
    #pragma unroll
    for (int fc = 0; fc < 4; ++fc) bfrag[fc] = bnext[fc];
  }
  #pragma unroll
  for (int fr = 0; fr < 4; ++fr) {
    int mrow = m0 + wr*64 + fr*16 + lk*4;
    #pragma unroll
    for (int fc = 0; fc < 4; ++fc) {
      int col = n0 + wc*64 + fc*16 + lrow;
      float bb = bias[col];
      #pragma unroll
      for (int i = 0; i < 4; ++i)
        tokens[(size_t)(mrow + i)*PROJ + col] = acc[fr][fc][i] + bb;
    }
  }
}

// ============== launcher ==============

extern "C" void kernel_launch(void* const* d_in, const int* in_sizes, int n_in,
                              void* d_out, int out_size, void* d_ws, size_t ws_size,
                              hipStream_t stream) {
  const float* images = (const float*)d_in[0];
  const float* gamma  = (const float*)d_in[1];
  const float* beta   = (const float*)d_in[2];
  const float* W      = (const float*)d_in[3];
  const float* bias   = (const float*)d_in[4];
  float* tokens  = (float*)d_out;
  float* patches = (float*)d_out + TOK_SIZE;

  const size_t WS_A_OFF = 6u << 20;                               // 6 MiB
  const size_t need = WS_A_OFF + (size_t)MT*KT*TILE_BYTES;        // ~98 MiB

  if (ws_size >= need) {
    char* Bws = (char*)d_ws;                                      // tiled bf16 B
    char* Aws = (char*)d_ws + WS_A_OFF;                           // tiled-BK32 bf16 A
    prepw_kernel<<<1744, 512, 0, stream>>>(images, gamma, beta, W,
                                           patches, Aws, Bws);
    gemm5b_kernel<<<MT*NT, 256, 0, stream>>>(Aws, Bws, bias, tokens);
  } else {
    float2* mrp = (float2*)d_ws;
    unsigned short* Wt = (unsigned short*)((char*)d_ws + (1 << 20));
    prep_kernel<<<M_TOT, 256, 0, stream>>>(images, patches, mrp);
    wtransr_kernel<<<dim3(24, KT), 256, 0, stream>>>(W, Wt);
    gemm_kernel<<<dim3(NT, MT), 256, 0, stream>>>(patches, mrp, gamma, beta, Wt, bias, tokens);
  }
}

// Round 17
// 148.588 us; speedup vs baseline: 1.0133x; 1.0133x over previous
//
#include <hip/hip_runtime.h>
#include <hip/hip_bf16.h>

#define IMG 224
#define NPS 14
#define NP  196
#define BATCH 64
#define PD  3840
#define PROJ 768
#define M_TOT (BATCH*NP)        // 12544
#define TOK_SIZE (M_TOT*PROJ)   // 9633792
#define KT  120                 // PD/32
#define MT  98                  // M_TOT/128
#define NT  6                   // PROJ/128
#define TILE_BYTES 8192         // 128x32 bf16 tile
#define IMG_BYTES 38535168      // 64*224*224*3*4

typedef __attribute__((ext_vector_type(8))) __bf16 bf16x8;
typedef __attribute__((ext_vector_type(4))) float f32x4;

__device__ __forceinline__ unsigned short f2bf(float f) {
    unsigned int u = __builtin_bit_cast(unsigned int, f);
    u += 0x7FFFu + ((u >> 16) & 1u);
    return (unsigned short)(u >> 16);
}

// prep-internal pbuf swizzle: XOR byte-addr bits[6:4] with bits[11:9].
__device__ __forceinline__ int swz(int a) { return a ^ (((a >> 9) & 7) << 4); }

#define GLD16(gsrc, ldst) __builtin_amdgcn_global_load_lds( \
    (const __attribute__((address_space(1))) unsigned int*)(gsrc), \
    (__attribute__((address_space(3))) unsigned int*)(ldst), 16, 0, 0)

// ============== FAST PATH (round-15 best: 148.9 us) ==============

// prepw: fused prep (blocks 0..1023) + W-transpose (blocks 1024..1743).
// prep path: tiled-BK32 Aws, paired full-line stores, T14 async split.
__global__ __launch_bounds__(512, 4) void prepw_kernel(
    const float* __restrict__ images, const float* __restrict__ gamma,
    const float* __restrict__ beta, const float* __restrict__ W,
    float* __restrict__ patches_out, char* __restrict__ Aws,
    char* __restrict__ Bws) {
  __shared__ __align__(16) char smem[32960];
  const int t = threadIdx.x;

  if (blockIdx.x >= 1024) {
    // ---------- W-transpose path ----------
    float (*wtile)[32][33] = (float (*)[32][33])smem;
    const int wb = blockIdx.x - 1024;
    const int half = t >> 8;          // 0 or 1
    const int tid = t & 255;
    const int nl = tid & 31;
    #pragma unroll
    for (int rep = 0; rep < 2; ++rep) {
      int idx = wb*4 + rep*2 + half;  // 0..2879
      int bx = idx % 24;              // n-tile
      int by = idx / 24;              // k-tile
      #pragma unroll
      for (int r = 0; r < 4; ++r) {
        int kl = (tid >> 5) + r*8;
        wtile[half][nl][kl] = W[(by*32 + kl)*PROJ + bx*32 + nl];
      }
      __syncthreads();
      if (tid < 128) {
        const int n_local = tid >> 2;
        const int kchunk  = tid & 3;
        unsigned int u[4];
        #pragma unroll
        for (int j = 0; j < 4; ++j) {
          unsigned short lo = f2bf(wtile[half][n_local][kchunk*8 + j*2]);
          unsigned short hi = f2bf(wtile[half][n_local][kchunk*8 + j*2 + 1]);
          u[j] = (unsigned)lo | ((unsigned)hi << 16);
        }
        const int n = bx*32 + n_local;
        const int ntile = n >> 7, nrow = n & 127;
        const int byteoff = (nrow*64 + (kchunk*8)*2) ^ ((nrow & 7) << 4);
        *(uint4*)(Bws + ((size_t)(ntile*KT + by))*TILE_BYTES + byteoff) =
            make_uint4(u[0], u[1], u[2], u[3]);
      }
      __syncthreads();
    }
    return;
  }

  // ---------- prep path ----------
  char* const pb = smem;
  float (*red_s)[8] = (float (*)[8])(smem + 32768);
  float (*red_q)[8] = (float (*)[8])(smem + 32832);

  int relv[2];
  int la[2][4];
  int iof8[2];
  unsigned jpk[2];
  #pragma unroll
  for (int u = 0; u < 2; ++u) {
    int uu = t + u*512;
    if (uu < 960) {
      int run = uu / 12, slot = uu - run*12;
      int g = run >> 4, p = run & 15;
      int dh = (g==0) ? 0 : ((g & 1) ? 8 : -8);
      int dw = (g==0) ? 0 : ((g <= 2) ? 8 : -8);
      int ioff = p + dh;
      relv[u] = ((ioff*224 + dw)*3 + slot*4)*4 + 32768;
      iof8[u] = ioff + 8;
      int i48 = slot*4;
      int q0 = i48/3, c0 = i48 - q0*3;
      int dbase = (p*16 + q0)*15 + g*3 + c0;
      int dd1 = (c0==2) ? 13 : 1;
      int dd2 = (c0==0) ? 2 : 14;
      la[u][0] = swz(dbase*4);
      la[u][1] = swz((dbase+dd1)*4);
      la[u][2] = swz((dbase+dd2)*4);
      la[u][3] = swz((dbase+15)*4);
      unsigned jp = 0;
      #pragma unroll
      for (int k = 0; k < 4; ++k) {
        int qk = q0 + ((c0 + k) >= 3 ? 1 : 0);
        jp |= (unsigned)(dw + qk + 8) << (8*k);
      }
      jpk[u] = jp;
    } else {
      relv[u] = 32768; iof8[u] = 0; jpk[u] = 0;
      la[u][0] = swz(4000*4); la[u][1] = swz(4001*4);
      la[u][2] = swz(4002*4); la[u][3] = swz(4003*4);
    }
  }

  const int d0 = (t < 480) ? t*8 : 0;
  const int rba = swz(d0*4);
  const int rbb = swz(d0*4 + 16);
  const int tileoff_t = (t >> 2)*TILE_BYTES;
  const int chunk16   = (t & 3)*16;
  float4 g8a = *(const float4*)(gamma + d0);
  float4 g8b = *(const float4*)(gamma + d0 + 4);
  float4 b8a = *(const float4*)(beta + d0);
  float4 b8b = *(const float4*)(beta + d0 + 4);

  auto do_loads = [&](int np, int toggle) -> float2 {
    int b  = np / NP;
    int pp = np - b*NP;
    int ph = pp / NPS;
    int pw = pp - ph*NPS;
    int pixoff = (b*50176 + (ph*224 + pw)*16)*12;
    const char* sbase = (const char*)images + (pixoff - 32768);
    float s = 0.f, q = 0.f;
    char* lb = pb + toggle;
    if (ph != 0 && ph != 13 && pw != 0 && pw != 13) {
      #pragma unroll
      for (int u = 0; u < 2; ++u) {
        if (u == 0 || t < 448) {
          float4 v4 = *(const float4*)(sbase + relv[u]);
          s += (v4.x + v4.y) + (v4.z + v4.w);
          q += (v4.x*v4.x + v4.y*v4.y) + (v4.z*v4.z + v4.w*v4.w);
          *(float*)(lb + la[u][0]) = v4.x;
          *(float*)(lb + la[u][1]) = v4.y;
          *(float*)(lb + la[u][2]) = v4.z;
          *(float*)(lb + la[u][3]) = v4.w;
        }
      }
    } else {
      int ph16 = ph*16 - 8, pw16 = pw*16 - 8;
      int lo = 32768 - pixoff;
      int hi = IMG_BYTES - pixoff + 32768 - 16;
      #pragma unroll
      for (int u = 0; u < 2; ++u) {
        if (u == 0 || t < 448) {
          int ii = ph16 + iof8[u];
          bool rowok = (unsigned)ii < 224u;
          int vo = rowok ? relv[u] : 32768;
          vo = vo < lo ? lo : vo;
          vo = vo > hi ? hi : vo;
          float4 v4 = *(const float4*)(sbase + vo);
          float vv0 = v4.x, vv1 = v4.y, vv2 = v4.z, vv3 = v4.w;
          #pragma unroll
          for (int k = 0; k < 4; ++k) {
            int jj = pw16 + (int)((jpk[u] >> (8*k)) & 255u);
            float x = (k==0?vv0:(k==1?vv1:(k==2?vv2:vv3)));
            x = (rowok && (unsigned)jj < 224u) ? x : 0.f;
            s += x; q += x*x;
            *(float*)(lb + la[u][k]) = x;
          }
        }
      }
    }
    return make_float2(s, q);
  };

  const int bi = blockIdx.x;
  const int start = 2*(bi*6 + (bi < 128 ? bi : 128));
  const int cnt = (bi < 128) ? 14 : 12;

  float2 curps = do_loads(start, 0);
  asm volatile("s_waitcnt lgkmcnt(0)" ::: "memory");
  __builtin_amdgcn_s_barrier();
  __builtin_amdgcn_sched_barrier(0);

  int cur = 0;
  unsigned ue0=0, ue1=0, ue2=0, ue3=0;

  for (int j = 0; j < cnt; ++j) {
    const int p_ = start + j;
    float4 va = *(const float4*)(pb + (cur << 14) + rba);
    float4 vb = *(const float4*)(pb + (cur << 14) + rbb);

    float4 w0 = make_float4(0.f,0.f,0.f,0.f);
    float4 w1 = make_float4(0.f,0.f,0.f,0.f);
    int pw16_n = 0, flags = 0;
    if (j + 1 < cnt) {
      int np = p_ + 1;
      int b  = np / NP;
      int pp = np - b*NP;
      int ph = pp / NPS;
      int pw = pp - ph*NPS;
      int pixoff = (b*50176 + (ph*224 + pw)*16)*12;
      const char* sbase = (const char*)images + (pixoff - 32768);
      if (ph != 0 && ph != 13 && pw != 0 && pw != 13) {
        flags = 3;
        w0 = *(const float4*)(sbase + relv[0]);
        if (t < 448) w1 = *(const float4*)(sbase + relv[1]);
      } else {
        int ph16 = ph*16 - 8;
        pw16_n = pw*16 - 8;
        int lo = 32768 - pixoff;
        int hi = IMG_BYTES - pixoff + 32768 - 16;
        flags = 4;
        {
          int ii = ph16 + iof8[0];
          bool rowok = (unsigned)ii < 224u;
          int vo = rowok ? relv[0] : 32768;
          vo = vo < lo ? lo : vo;
          vo = vo > hi ? hi : vo;
          w0 = *(const float4*)(sbase + vo);
          if (rowok) flags |= 1;
        }
        if (t < 448) {
          int ii = ph16 + iof8[1];
          bool rowok = (unsigned)ii < 224u;
          int vo = rowok ? relv[1] : 32768;
          vo = vo < lo ? lo : vo;
          vo = vo > hi ? hi : vo;
          w1 = *(const float4*)(sbase + vo);
          if (rowok) flags |= 2;
        }
      }
    }

    float s = curps.x, q = curps.y;
    #pragma unroll
    for (int o = 32; o > 0; o >>= 1) { s += __shfl_xor(s, o); q += __shfl_xor(q, o); }
    if ((t & 63) == 0) { red_s[cur][t >> 6] = s; red_q[cur][t >> 6] = q; }
    asm volatile("s_waitcnt lgkmcnt(0)" ::: "memory");
    __builtin_amdgcn_s_barrier();
    __builtin_amdgcn_sched_barrier(0);

    {
      const float* rs = red_s[cur]; const float* rq = red_q[cur];
      float4 sa = *(const float4*)rs;  float4 sb = *(const float4*)(rs + 4);
      float4 qa = *(const float4*)rq;  float4 qb = *(const float4*)(rq + 4);
      float S = ((sa.x+sa.y)+(sa.z+sa.w)) + ((sb.x+sb.y)+(sb.z+sb.w));
      float Q = ((qa.x+qa.y)+(qa.z+qa.w)) + ((qb.x+qb.y)+(qb.z+qb.w));
      float mean = S * (1.f/PD);
      float rstd = rsqrtf(Q*(1.f/PD) - mean*mean + 1e-6f);
      if (t < 480) {
        float* po = patches_out + (size_t)p_*PD + d0;
        f32x4 vva = __builtin_bit_cast(f32x4, va);
        f32x4 vvb = __builtin_bit_cast(f32x4, vb);
        __builtin_nontemporal_store(vva, (f32x4*)po);
        __builtin_nontemporal_store(vvb, (f32x4*)(po + 4));
        float f0 = fmaf(va.x - mean, rstd*g8a.x, b8a.x);
        float f1 = fmaf(va.y - mean, rstd*g8a.y, b8a.y);
        float f2 = fmaf(va.z - mean, rstd*g8a.z, b8a.z);
        float f3 = fmaf(va.w - mean, rstd*g8a.w, b8a.w);
        float f4 = fmaf(vb.x - mean, rstd*g8b.x, b8b.x);
        float f5 = fmaf(vb.y - mean, rstd*g8b.y, b8b.y);
        float f6 = fmaf(vb.z - mean, rstd*g8b.z, b8b.z);
        float f7 = fmaf(vb.w - mean, rstd*g8b.w, b8b.w);
        unsigned u0, u1, u2, u3;
        asm("v_cvt_pk_bf16_f32 %0, %1, %2" : "=v"(u0) : "v"(f0), "v"(f1));
        asm("v_cvt_pk_bf16_f32 %0, %1, %2" : "=v"(u1) : "v"(f2), "v"(f3));
        asm("v_cvt_pk_bf16_f32 %0, %1, %2" : "=v"(u2) : "v"(f4), "v"(f5));
        asm("v_cvt_pk_bf16_f32 %0, %1, %2" : "=v"(u3) : "v"(f6), "v"(f7));
        if ((j & 1) == 0) {
          ue0 = u0; ue1 = u1; ue2 = u2; ue3 = u3;
        } else {
          const int mrow1 = p_ & 127;
          const int mrow0 = mrow1 - 1;
          size_t tbase = (size_t)(p_ >> 7)*(KT*TILE_BYTES) + tileoff_t;
          int off0 = (mrow0*64 + chunk16) ^ ((mrow0 & 7) << 4);
          int off1 = (mrow1*64 + chunk16) ^ ((mrow1 & 7) << 4);
          *(uint4*)(Aws + tbase + off0) = make_uint4(ue0, ue1, ue2, ue3);
          *(uint4*)(Aws + tbase + off1) = make_uint4(u0, u1, u2, u3);
        }
      }
    }

    float2 nps = make_float2(0.f, 0.f);
    if (j + 1 < cnt) {
      char* lb = pb + ((cur ^ 1) << 14);
      float ss = 0.f, qq = 0.f;
      if (!(flags & 4)) {
        ss += (w0.x + w0.y) + (w0.z + w0.w);
        qq += (w0.x*w0.x + w0.y*w0.y) + (w0.z*w0.z + w0.w*w0.w);
        *(float*)(lb + la[0][0]) = w0.x;
        *(float*)(lb + la[0][1]) = w0.y;
        *(float*)(lb + la[0][2]) = w0.z;
        *(float*)(lb + la[0][3]) = w0.w;
        if (t < 448) {
          ss += (w1.x + w1.y) + (w1.z + w1.w);
          qq += (w1.x*w1.x + w1.y*w1.y) + (w1.z*w1.z + w1.w*w1.w);
          *(float*)(lb + la[1][0]) = w1.x;
          *(float*)(lb + la[1][1]) = w1.y;
          *(float*)(lb + la[1][2]) = w1.z;
          *(float*)(lb + la[1][3]) = w1.w;
        }
      } else {
        #pragma unroll
        for (int u = 0; u < 2; ++u) {
          if (u == 0 || t < 448) {
            float4 v4 = u ? w1 : w0;
            bool rowok = (flags >> u) & 1;
            float vv0 = v4.x, vv1 = v4.y, vv2 = v4.z, vv3 = v4.w;
            #pragma unroll
            for (int k = 0; k < 4; ++k) {
              int jj = pw16_n + (int)((jpk[u] >> (8*k)) & 255u);
              float x = (k==0?vv0:(k==1?vv1:(k==2?vv2:vv3)));
              x = (rowok && (unsigned)jj < 224u) ? x : 0.f;
              ss += x; qq += x*x;
              *(float*)(lb + la[u][k]) = x;
            }
          }
        }
      }
      nps = make_float2(ss, qq);
    }

    asm volatile("s_waitcnt lgkmcnt(0)" ::: "memory");
    __builtin_amdgcn_s_barrier();
    __builtin_amdgcn_sched_barrier(0);
    curps = nps; cur ^= 1;
  }
}

// gemm5b: gemm5 with ring-4 A staging (stage lifetime 2->3 iterations).
// Ledger: kt=0 vmcnt(4); 1<=kt<=117 vmcnt(2); kt>=118 vmcnt(0).
__global__ __launch_bounds__(256) void gemm5b_kernel(
    const char* __restrict__ Aws, const char* __restrict__ Bws,
    const float* __restrict__ bias, float* __restrict__ tokens) {
  __shared__ __align__(16) char lds4[4][TILE_BYTES];   // 32 KB, A only
  const int bid = blockIdx.x;
  const int xcd = bid & 7, pos = bid >> 3;
  const int virt = (xcd < 4) ? xcd*74 + pos : 296 + (xcd - 4)*73 + pos;
  const int bm = virt / 6;
  const int bn = virt - bm*6;

  const int t = threadIdx.x;
  const int l = t & 63;
  const int w = t >> 6;
  const int wr = w >> 1, wc = w & 1;
  const int lrow = l & 15;
  const int lk   = l >> 4;

  const char* Ag = Aws + (size_t)bm*KT*TILE_BYTES;
  const char* Bg = Bws + (size_t)bn*KT*TILE_BYTES;
  const int ga0 = w*1024 + l*16;
  const int ga1 = 4096 + w*1024 + l*16;
  const int da0 = w*1024;
  const int da1 = 4096 + w*1024;

  int aoff[4], bloc[4];
  #pragma unroll
  for (int fr = 0; fr < 4; ++fr) {
    int row = wr*64 + fr*16 + lrow;
    aoff[fr] = (row*64 + lk*16) ^ ((row & 7) << 4);
  }
  #pragma unroll
  for (int fc = 0; fc < 4; ++fc) {
    int row = wc*64 + fc*16 + lrow;
    bloc[fc] = (row*64 + lk*16) ^ ((row & 7) << 4);
  }

  f32x4 acc[4][4];
  #pragma unroll
  for (int i = 0; i < 4; ++i)
    #pragma unroll
    for (int j = 0; j < 4; ++j) acc[i][j] = f32x4{0.f, 0.f, 0.f, 0.f};

  auto STAGE_A = [&](int kt, char* base) {
    const size_t off = (size_t)kt * TILE_BYTES;
    GLD16(Ag + off + ga0, base + da0);
    GLD16(Ag + off + ga1, base + da1);
  };

  char* curb = &lds4[0][0];
  char* n1   = &lds4[1][0];
  char* n2   = &lds4[2][0];
  char* spare= &lds4[3][0];

  bf16x8 bf[4];
  #pragma unroll
  for (int fc = 0; fc < 4; ++fc) bf[fc] = *(const bf16x8*)(Bg + bloc[fc]);
  __builtin_amdgcn_sched_barrier(0);
  STAGE_A(0, curb);
  STAGE_A(1, n1);
  STAGE_A(2, n2);

  for (int kt = 0; kt < KT; ++kt) {
    if (kt == 0)           asm volatile("s_waitcnt vmcnt(4)" ::: "memory");
    else if (kt < KT - 2)  asm volatile("s_waitcnt vmcnt(2)" ::: "memory");
    else                   asm volatile("s_waitcnt vmcnt(0)" ::: "memory");
    __builtin_amdgcn_s_barrier();
    __builtin_amdgcn_sched_barrier(0);
    bf16x8 af[4];
    #pragma unroll
    for (int fr = 0; fr < 4; ++fr) af[fr] = *(const bf16x8*)(curb + aoff[fr]);
    #pragma unroll
    for (int fr = 0; fr < 4; ++fr)
      #pragma unroll
      for (int fc = 0; fc < 4; ++fc)
        acc[fr][fc] = __builtin_amdgcn_mfma_f32_16x16x32_bf16(
            af[fr], bf[fc], acc[fr][fc], 0, 0, 0);
    if (kt + 1 < KT) {
      const char* bsrc = Bg + (size_t)(kt + 1)*TILE_BYTES;
      #pragma unroll
      for (int fc = 0; fc < 4; ++fc) bf[fc] = *(const bf16x8*)(bsrc + bloc[fc]);
    }
    __builtin_amdgcn_sched_barrier(0);
    if (kt + 3 < KT) STAGE_A(kt + 3, spare);
    char* tmp = curb; curb = n1; n1 = n2; n2 = spare; spare = tmp;
  }

  const int m0 = bm * 128, n0 = bn * 128;
  #pragma unroll
  for (int fr = 0; fr < 4; ++fr) {
    int mrow = m0 + wr*64 + fr*16 + lk*4;
    #pragma unroll
    for (int fc = 0; fc < 4; ++fc) {
      int col = n0 + wc*64 + fc*16 + lrow;
      float bb = bias[col];
      #pragma unroll
      for (int i = 0; i < 4; ++i)
        __builtin_nontemporal_store(acc[fr][fc][i] + bb,
                                    &tokens[(size_t)(mrow + i)*PROJ + col]);
    }
  }
}

// ============== FALLBACK PATH (round-1, known-passing) ==============

__global__ __launch_bounds__(256) void prep_kernel(
    const float* __restrict__ images, float* __restrict__ patches_out,
    float2* __restrict__ mr) {
  const int pid = blockIdx.x;
  const int b  = pid / NP;
  const int pp = pid - b*NP;
  const int ph = pp / NPS;
  const int pw = pp - ph*NPS;
  const int t = threadIdx.x;
  float s = 0.f, s2 = 0.f;
  #pragma unroll
  for (int r = 0; r < 15; ++r) {
    int d   = t + r*256;
    int ch5 = d % 15;
    int rem = d / 15;
    int q = rem & 15;
    int p = rem >> 4;
    int g = ch5 / 3;
    int c = ch5 - g*3;
    int dh = (g==0) ? 0 : ((g & 1) ? 8 : -8);
    int dw = (g==0) ? 0 : ((g <= 2) ? 8 : -8);
    int ii = ph*16 + p + dh;
    int jj = pw*16 + q + dw;
    float v = 0.f;
    if ((unsigned)ii < IMG && (unsigned)jj < IMG)
      v = images[((b*IMG + ii)*IMG + jj)*3 + c];
    s += v; s2 += v*v;
    patches_out[(size_t)pid*PD + d] = v;
  }
  #pragma unroll
  for (int o = 32; o > 0; o >>= 1) { s += __shfl_xor(s, o); s2 += __shfl_xor(s2, o); }
  __shared__ float red[8];
  int w = t >> 6;
  if ((t & 63) == 0) { red[w*2] = s; red[w*2+1] = s2; }
  __syncthreads();
  if (t == 0) {
    float S  = red[0]+red[2]+red[4]+red[6];
    float S2 = red[1]+red[3]+red[5]+red[7];
    float mean = S * (1.f/PD);
    float var  = S2 * (1.f/PD) - mean*mean;
    mr[pid] = make_float2(mean, rsqrtf(var + 1e-6f));
  }
}

__global__ __launch_bounds__(256) void wtransr_kernel(
    const float* __restrict__ W, unsigned short* __restrict__ Wt) {
  __shared__ float tile[32][33];
  const int bx = blockIdx.x;
  const int by = blockIdx.y;
  const int tx = threadIdx.x & 31;
  const int ty = threadIdx.x >> 5;
  #pragma unroll
  for (int r = 0; r < 4; ++r)
    tile[ty + r*8][tx] = W[(by*32 + ty + r*8)*PROJ + bx*32 + tx];
  __syncthreads();
  #pragma unroll
  for (int r = 0; r < 4; ++r)
    Wt[(size_t)(bx*32 + ty + r*8)*PD + by*32 + tx] = f2bf(tile[tx][ty + r*8]);
}

__global__ __launch_bounds__(256) void gemm_kernel(
    const float* __restrict__ patches, const float2* __restrict__ mr,
    const float* __restrict__ gamma, const float* __restrict__ beta,
    const unsigned short* __restrict__ Wt, const float* __restrict__ bias,
    float* __restrict__ tokens) {
  __shared__ unsigned short Alds[128][40];
  const int bn = blockIdx.x;
  const int bm = blockIdx.y;
  const int t = threadIdx.x;
  const int l = t & 63;
  const int w = t >> 6;
  const int wr = w >> 1, wc = w & 1;
  const int m0 = bm * 128, n0 = bn * 128;
  const int lrow = l & 15, lk = l >> 4;
  const unsigned short* bp[4];
  #pragma unroll
  for (int fc = 0; fc < 4; ++fc)
    bp[fc] = Wt + (size_t)(n0 + wc*64 + fc*16 + lrow) * PD + lk*8;
  const int srow = t >> 3;
  const int skq  = (t & 7) * 4;
  f32x4 acc[4][4];
  #pragma unroll
  for (int i = 0; i < 4; ++i)
    #pragma unroll
    for (int j = 0; j < 4; ++j) acc[i][j] = f32x4{0.f, 0.f, 0.f, 0.f};
  bf16x8 bfrag[4], bnext[4];
  #pragma unroll
  for (int fc = 0; fc < 4; ++fc) bfrag[fc] = *reinterpret_cast<const bf16x8*>(bp[fc]);
  for (int kt = 0; kt < KT; ++kt) {
    const int k0 = kt * 32;
    #pragma unroll
    for (int pass = 0; pass < 4; ++pass) {
      int row = pass*32 + srow;
      int m = m0 + row;
      float2 mrv = mr[m];
      const float4 v  = *reinterpret_cast<const float4*>(patches + (size_t)m*PD + k0 + skq);
      const float4 gv = *reinterpret_cast<const float4*>(gamma + k0 + skq);
      const float4 bv = *reinterpret_cast<const float4*>(beta  + k0 + skq);
      ushort4 o;
      o.x = f2bf((v.x - mrv.x)*mrv.y*gv.x + bv.x);
      o.y = f2bf((v.y - mrv.x)*mrv.y*gv.y + bv.y);
      o.z = f2bf((v.z - mrv.x)*mrv.y*gv.z + bv.z);
      o.w = f2bf((v.w - mrv.x)*mrv.y*gv.w + bv.w);
      *reinterpret_cast<ushort4*>(&Alds[row][skq]) = o;
    }
    if (kt < KT-1) {
      #pragma unroll
      for (int fc = 0; fc < 4; ++fc)
        bnext[fc] = *reinterpret_cast<const bf16x8*>(bp[fc] + k0 + 32);
    }
    __syncthreads();
    bf16x8 afrag[4];
    #pragma unroll
    for (int fr = 0; fr < 4; ++fr)
      afrag[fr] = *reinterpret_cast<const bf16x8*>(&Alds[wr*64 + fr*16 + lrow][lk*8]);
    #pragma unroll
    for (int fr = 0; fr < 4; ++fr)
      #pragma unroll
      for (int fc = 0; fc < 4; ++fc)
        acc[fr][fc] = __builtin_amdgcn_mfma_f32_16x16x32_bf16(
            afrag[fr], bfrag[fc], acc[fr][fc], 0, 0, 0);
    __syncthreads();
    #pragma unroll
    for (int fc = 0; fc < 4; ++fc) bfrag[fc] = bnext[fc];
  }
  #pragma unroll
  for (int fr = 0; fr < 4; ++fr) {
    int mrow = m0 + wr*64 + fr*16 + lk*4;
    #pragma unroll
    for (int fc = 0; fc < 4; ++fc) {
      int col = n0 + wc*64 + fc*16 + lrow;
      float bb = bias[col];
      #pragma unroll
      for (int i = 0; i < 4; ++i)
        tokens[(size_t)(mrow + i)*PROJ + col] = acc[fr][fc][i] + bb;
    }
  }
}

// ============== launcher ==============

extern "C" void kernel_launch(void* const* d_in, const int* in_sizes, int n_in,
                              void* d_out, int out_size, void* d_ws, size_t ws_size,
                              hipStream_t stream) {
  const float* images = (const float*)d_in[0];
  const float* gamma  = (const float*)d_in[1];
  const float* beta   = (const float*)d_in[2];
  const float* W      = (const float*)d_in[3];
  const float* bias   = (const float*)d_in[4];
  float* tokens  = (float*)d_out;
  float* patches = (float*)d_out + TOK_SIZE;

  const size_t WS_A_OFF = 6u << 20;                               // 6 MiB
  const size_t need = WS_A_OFF + (size_t)MT*KT*TILE_BYTES;        // ~98 MiB

  if (ws_size >= need) {
    char* Bws = (char*)d_ws;                                      // tiled bf16 B
    char* Aws = (char*)d_ws + WS_A_OFF;                           // tiled-BK32 bf16 A
    prepw_kernel<<<1744, 512, 0, stream>>>(images, gamma, beta, W,
                                           patches, Aws, Bws);
    gemm5b_kernel<<<MT*NT, 256, 0, stream>>>(Aws, Bws, bias, tokens);
  } else {
    float2* mrp = (float2*)d_ws;
    unsigned short* Wt = (unsigned short*)((char*)d_ws + (1 << 20));
    prep_kernel<<<M_TOT, 256, 0, stream>>>(images, patches, mrp);
    wtransr_kernel<<<dim3(24, KT), 256, 0, stream>>>(W, Wt);
    gemm_kernel<<<dim3(NT, MT), 256, 0, stream>>>(patches, mrp, gamma, beta, Wt, bias, tokens);
  }
}